// Round 15
// baseline (59.163 us; speedup 1.0000x reference)
//
#include <hip/hip_runtime.h>
#include <hip/hip_bf16.h>
#include <math.h>

#define NB 512
#define NT 256
#define NC 384
#define NH 64

typedef __bf16 bf16x8 __attribute__((ext_vector_type(8)));
typedef unsigned short u16x8 __attribute__((ext_vector_type(8)));
typedef unsigned short u16x4 __attribute__((ext_vector_type(4)));
typedef unsigned int   u32x4 __attribute__((ext_vector_type(4)));
typedef float f32x4 __attribute__((ext_vector_type(4)));

// native RTNE f32->bf16 (compiler emits v_cvt_pk_bf16_f32 for pairs; m240)
__device__ __forceinline__ unsigned short f2bf(float f) {
    const __bf16 h = (__bf16)f;
    return __builtin_bit_cast(unsigned short, h);
}

__device__ __forceinline__ unsigned pack2(float a, float b) {
    return (unsigned)f2bf(a) | ((unsigned)f2bf(b) << 16);
}

__device__ __forceinline__ f32x4 mfma16(bf16x8 a, bf16x8 b, f32x4 c) {
    return __builtin_amdgcn_mfma_f32_16x16x32_bf16(a, b, c, 0, 0, 0);
}

// ============ fused head, 16 waves, async dbuf staging, 1 barrier/chunk ========
// (v10 + native bf16 converts + T5 setprio around phase-3 MFMA clusters.)
// LDS (shorts):  Q [256][72] @0 | K [256][72] @18432 | VT [64][264] @36864
//                XS[2][32][392] @53760 (ping-pong x staging, 8 chunks of 32 rows)
// Phase 2: wave j<12 owns (pass=j>>2, n=j&3) with its 12 W frags in regs
//          (gathered directly from L3-resident Wq/Wk/Wv in the prologue).
// Phase 3: wave w owns q-tile T(w), permuted so each SIMD gets 34 score-tiles.
// NOTE spill cliff (r5/r8/r9/r12): nothing with a >=32-reg footprint may stay
// live across phase 3; Bw dies at end of phase 2.
#define FOFF_Q   0
#define FLDQK    72
#define FOFF_K   18432
#define FOFF_VT  36864
#define FLDVT    264
#define FOFF_XS0 53760
#define FOFF_XS1 66304
#define FLDXS    392
#define FSMEM    78848          // shorts = 157,696 B -> 1 block/CU, 16 waves

__global__ __launch_bounds__(1024, 1) void head_v11(
    const float* __restrict__ x, const float* __restrict__ Wq,
    const float* __restrict__ Wk, const float* __restrict__ Wv,
    float* __restrict__ out)
{
    __shared__ __align__(16) unsigned short SM[FSMEM];

    const int b    = blockIdx.x;
    const int tid  = threadIdx.x;
    const int w    = tid >> 6;       // wave 0..15
    const int lane = tid & 63;
    const int g    = lane >> 4;
    const int col  = lane & 15;

    // balanced q-tile permutation: each SIMD (w&3) totals 34 score-tiles
    const int wq2 = w >> 2;
    const int T = (wq2 == 0) ? w : (wq2 == 1) ? (19 - w) : (wq2 == 2) ? (15 - w) : (w - 4);

    // per-thread staging geometry: 32 rows x 384 f32 = 1024 thr x 3 float4
    const int srow[3] = { (tid * 4) / 384, (4096 + tid * 4) / 384, (8192 + tid * 4) / 384 };
    const int scol[3] = { (tid * 4) % 384, (4096 + tid * 4) % 384, (8192 + tid * 4) % 384 };

    // ---- prologue: issue chunk0 loads first ----
    float4 pre[3];
    {
        const float* xb = x + (size_t)b * NT * NC;
        #pragma unroll
        for (int k = 0; k < 3; ++k)
            pre[k] = *reinterpret_cast<const float4*>(xb + k * 4096 + tid * 4);
    }

    // ---- phase-2 job: wave j<12 owns (pass, n); gather its 12 W frags --------
    // Bw[kk] elem j = W_pass[(kk*32+8g+j)*64 + n*16+col]
    const int pass = w >> 2;         // 0=Q 1=K 2=V (w<12)
    const int n    = w & 3;
    bf16x8 Bw[12];
    if (w < 12) {
        const float* Wsel = (pass == 0) ? Wq : (pass == 1) ? Wk : Wv;
        const float* Wbase = Wsel + (size_t)(g * 8) * 64 + n * 16 + col;
        #pragma unroll
        for (int kk = 0; kk < 12; ++kk) {
            u16x8 u;
            #pragma unroll
            for (int j = 0; j < 8; ++j)
                u[j] = f2bf(Wbase[(size_t)(kk * 32 + j) * 64]);
            Bw[kk] = __builtin_bit_cast(bf16x8, u);
        }
    }

    // write chunk0 to XS0
    #pragma unroll
    for (int k = 0; k < 3; ++k) {
        u16x4 u;
        u[0] = f2bf(pre[k].x); u[1] = f2bf(pre[k].y);
        u[2] = f2bf(pre[k].z); u[3] = f2bf(pre[k].w);
        *reinterpret_cast<u16x4*>(&SM[FOFF_XS0 + srow[k] * FLDXS + scol[k]]) = u;
    }
    __syncthreads();

    // ---- main loop: 8 chunks of 32 rows, ping-pong, ONE barrier per chunk ----
    #pragma unroll 1
    for (int ch = 0; ch < 8; ++ch) {
        // issue next chunk's global loads FIRST (latency hides under compute)
        float4 nxt[3];
        if (ch < 7) {
            const float* xb = x + ((size_t)b * NT + (ch + 1) * 32) * NC;
            #pragma unroll
            for (int k = 0; k < 3; ++k)
                nxt[k] = *reinterpret_cast<const float4*>(xb + k * 4096 + tid * 4);
        }

        // compute chunk ch from buf[ch&1]
        const int xsbase = (ch & 1) ? FOFF_XS1 : FOFF_XS0;
        if (w < 12) {
            #pragma unroll
            for (int rt = 0; rt < 2; ++rt) {        // two 16-row tiles per chunk
                const int tile = ch * 2 + rt;
                f32x4 acc = (f32x4){0.f, 0.f, 0.f, 0.f};
                #pragma unroll
                for (int kk = 0; kk < 12; ++kk) {
                    const bf16x8 xf = *reinterpret_cast<const bf16x8*>(
                        &SM[xsbase + (rt * 16 + col) * FLDXS + kk * 32 + g * 8]);
                    acc = mfma16(xf, Bw[kk], acc);
                }
                const int tb = tile * 16 + g * 4;
                if (pass < 2) {
                    const int base = (pass == 0) ? FOFF_Q : FOFF_K;
                    #pragma unroll
                    for (int r = 0; r < 4; ++r)
                        SM[base + (tb + r) * FLDQK + n * 16 + col] = f2bf(acc[r]);
                } else {
                    #pragma unroll
                    for (int r = 0; r < 4; ++r)
                        SM[FOFF_VT + (n * 16 + col) * FLDVT + tb + r] = f2bf(acc[r]);
                }
            }
        }

        // write next chunk into the buffer compute(ch-1) used; its readers were
        // fenced by the previous iteration's barrier -> no hazard with compute(ch)
        if (ch < 7) {
            const int nb = ((ch + 1) & 1) ? FOFF_XS1 : FOFF_XS0;
            #pragma unroll
            for (int k = 0; k < 3; ++k) {
                u16x4 u;
                u[0] = f2bf(nxt[k].x); u[1] = f2bf(nxt[k].y);
                u[2] = f2bf(nxt[k].z); u[3] = f2bf(nxt[k].w);
                *reinterpret_cast<u16x4*>(&SM[nb + srow[k] * FLDXS + scol[k]]) = u;
            }
        }
        __syncthreads();    // publishes chunk ch+1 AND compute(ch)'s Q/K/VT tiles
    }

    // ---------------- phase 3: attention (swapped QK^T, shuffle PV) ----------
    const int hi_half = (lane >> 5) & 1;
    const int srcA = ((lane >> 4) & 1) * 32 + col;
    const int srcB = srcA + 16;

    // Q B-frags from LDS rows
    bf16x8 qb[2];
    #pragma unroll
    for (int kk = 0; kk < 2; ++kk)
        qb[kk] = *reinterpret_cast<const bf16x8*>(
            &SM[FOFF_Q + (T * 16 + col) * FLDQK + kk * 32 + g * 8]);

    // scores S^T: lane holds S[s=nt*16+4g+r][t=T*16+col]
    f32x4 sc[16];
    __builtin_amdgcn_s_setprio(1);             // T5: favor MFMA wave (indep waves)
    #pragma unroll
    for (int nt = 0; nt < 16; ++nt) {
        if (nt <= T) {
            f32x4 a = {0.f, 0.f, 0.f, 0.f};
            const bf16x8 ka0 = *reinterpret_cast<const bf16x8*>(
                &SM[FOFF_K + (nt * 16 + col) * FLDQK + g * 8]);
            const bf16x8 ka1 = *reinterpret_cast<const bf16x8*>(
                &SM[FOFF_K + (nt * 16 + col) * FLDQK + 32 + g * 8]);
            a = mfma16(ka0, qb[0], a);
            a = mfma16(ka1, qb[1], a);
            sc[nt] = a;
        }
    }
    __builtin_amdgcn_s_setprio(0);

    // softmax over s for row t=col; reduce across g with 2 shuffles
    float m = -INFINITY;
    #pragma unroll
    for (int nt = 0; nt < 16; ++nt) {
        if (nt <= T) {
            #pragma unroll
            for (int r = 0; r < 4; ++r) {
                float v = sc[nt][r] * 0.125f;
                if (nt == T && (4 * g + r) > col) v = -INFINITY;   // causal
                sc[nt][r] = v;
                m = fmaxf(m, v);
            }
        }
    }
    m = fmaxf(m, __shfl_xor(m, 16));
    m = fmaxf(m, __shfl_xor(m, 32));
    float s = 0.f;
    #pragma unroll
    for (int nt = 0; nt < 16; ++nt) {
        if (nt <= T) {
            #pragma unroll
            for (int r = 0; r < 4; ++r) {
                const float p = __expf(sc[nt][r] - m);
                sc[nt][r] = p;
                s += p;
            }
        }
    }
    s += __shfl_xor(s, 16);
    s += __shfl_xor(s, 32);
    const float inv = 1.0f / s;

    // normalized P -> bf16 pairs (per nt: r0|r1, r2|r3)
    unsigned P4lo[16], P4hi[16];
    #pragma unroll
    for (int nt = 0; nt < 16; ++nt) {
        if (nt <= T) {
            P4lo[nt] = pack2(sc[nt][0] * inv, sc[nt][1] * inv);
            P4hi[nt] = pack2(sc[nt][2] * inv, sc[nt][3] * inv);
        } else { P4lo[nt] = 0u; P4hi[nt] = 0u; }
    }

    // PV: build P A-frags via shuffles (no LDS), accumulate O
    f32x4 oacc[4];
    #pragma unroll
    for (int nn = 0; nn < 4; ++nn) oacc[nn] = (f32x4){0.f, 0.f, 0.f, 0.f};
    #pragma unroll
    for (int cpv = 0; cpv < 8; ++cpv) {
        if (cpv <= (T >> 1)) {
            const unsigned a0 = __shfl(P4lo[2 * cpv],     srcA, 64);
            const unsigned a1 = __shfl(P4lo[2 * cpv + 1], srcA, 64);
            const unsigned b0 = __shfl(P4hi[2 * cpv],     srcA, 64);
            const unsigned b1 = __shfl(P4hi[2 * cpv + 1], srcA, 64);
            const unsigned c0 = __shfl(P4lo[2 * cpv],     srcB, 64);
            const unsigned c1 = __shfl(P4lo[2 * cpv + 1], srcB, 64);
            const unsigned d0 = __shfl(P4hi[2 * cpv],     srcB, 64);
            const unsigned d1 = __shfl(P4hi[2 * cpv + 1], srcB, 64);
            u32x4 wv;
            wv[0] = hi_half ? a1 : a0;
            wv[1] = hi_half ? b1 : b0;
            wv[2] = hi_half ? c1 : c0;
            wv[3] = hi_half ? d1 : d0;
            const bf16x8 pa = __builtin_bit_cast(bf16x8, wv);
            __builtin_amdgcn_s_setprio(1);
            #pragma unroll
            for (int nn = 0; nn < 4; ++nn) {
                const bf16x8 vb = *reinterpret_cast<const bf16x8*>(
                    &SM[FOFF_VT + (nn * 16 + col) * FLDVT + cpv * 32 + g * 8]);
                oacc[nn] = mfma16(pa, vb, oacc[nn]);
            }
            __builtin_amdgcn_s_setprio(0);
        }
    }

    // store O (P already normalized)
    #pragma unroll
    for (int nn = 0; nn < 4; ++nn)
        #pragma unroll
        for (int r = 0; r < 4; ++r)
            out[((size_t)b * NT + T * 16 + 4 * g + r) * NH + nn * 16 + col] = oacc[nn][r];
}

// ============ launcher =========================================================
extern "C" void kernel_launch(void* const* d_in, const int* in_sizes, int n_in,
                              void* d_out, int out_size, void* d_ws, size_t ws_size,
                              hipStream_t stream) {
    (void)in_sizes; (void)n_in; (void)out_size; (void)d_ws; (void)ws_size;
    const float* x  = (const float*)d_in[0];
    const float* wq = (const float*)d_in[1];
    const float* wk = (const float*)d_in[2];
    const float* wv = (const float*)d_in[3];
    float* o = (float*)d_out;

    head_v11<<<dim3(NB), dim3(1024), 0, stream>>>(x, wq, wk, wv, o);
}

// Round 16
// 56.963 us; speedup vs baseline: 1.0386x; 1.0386x over previous
//
#include <hip/hip_runtime.h>
#include <hip/hip_bf16.h>
#include <math.h>

#define NB 512
#define NT 256
#define NC 384
#define NH 64

typedef __bf16 bf16x8 __attribute__((ext_vector_type(8)));
typedef unsigned short u16x8 __attribute__((ext_vector_type(8)));
typedef unsigned short u16x4 __attribute__((ext_vector_type(4)));
typedef unsigned int   u32x4 __attribute__((ext_vector_type(4)));
typedef float f32x4 __attribute__((ext_vector_type(4)));

__device__ __forceinline__ unsigned short f2bf(float f) {
    union { float f; unsigned u; } v; v.f = f;
    unsigned r = v.u + 0x7FFFu + ((v.u >> 16) & 1u);   // round-to-nearest-even
    return (unsigned short)(r >> 16);
}

__device__ __forceinline__ unsigned pack2(float a, float b) {
    return (unsigned)f2bf(a) | ((unsigned)f2bf(b) << 16);
}

__device__ __forceinline__ f32x4 mfma16(bf16x8 a, bf16x8 b, f32x4 c) {
    return __builtin_amdgcn_mfma_f32_16x16x32_bf16(a, b, c, 0, 0, 0);
}

// ============ fused head, 16 waves, async dbuf staging, 1 barrier/chunk ========
// FINAL (r14's v10, session best: 57.2 us, 1.9x over baseline).
// LDS (shorts):  Q [256][72] @0 | K [256][72] @18432 | VT [64][264] @36864
//                XS[2][32][392] @53760 (ping-pong x staging, 8 chunks of 32 rows)
// Phase 2: wave j<12 owns (pass=j>>2, n=j&3) with its 12 W frags in regs
//          (gathered directly from L3-resident Wq/Wk/Wv in the prologue).
// Phase 3: wave w owns q-tile T(w), permuted so each SIMD gets 34 score-tiles;
//          swapped QK^T (S^T in regs), 2-shuffle softmax, shuffle-built PV frags.
// Closed doors (measured this session): 2 blocks/CU & cross-batch pipeline spill
// (>=32-reg array live across phase 3 -> scratch, r5/r8/r9/r12); barrier halving
// +0.3us; setprio & native-cvt null/negative (r15); Wf-dispatch fold +1us (r13);
// T14 async-stage +17% (r11) and wave-specialized projection +6% (r10) retained.
#define FOFF_Q   0
#define FLDQK    72
#define FOFF_K   18432
#define FOFF_VT  36864
#define FLDVT    264
#define FOFF_XS0 53760
#define FOFF_XS1 66304
#define FLDXS    392
#define FSMEM    78848          // shorts = 157,696 B -> 1 block/CU, 16 waves

__global__ __launch_bounds__(1024, 1) void head_v10(
    const float* __restrict__ x, const float* __restrict__ Wq,
    const float* __restrict__ Wk, const float* __restrict__ Wv,
    float* __restrict__ out)
{
    __shared__ __align__(16) unsigned short SM[FSMEM];

    const int b    = blockIdx.x;
    const int tid  = threadIdx.x;
    const int w    = tid >> 6;       // wave 0..15
    const int lane = tid & 63;
    const int g    = lane >> 4;
    const int col  = lane & 15;

    // balanced q-tile permutation: each SIMD (w&3) totals 34 score-tiles
    const int wq2 = w >> 2;
    const int T = (wq2 == 0) ? w : (wq2 == 1) ? (19 - w) : (wq2 == 2) ? (15 - w) : (w - 4);

    // per-thread staging geometry: 32 rows x 384 f32 = 1024 thr x 3 float4
    const int srow[3] = { (tid * 4) / 384, (4096 + tid * 4) / 384, (8192 + tid * 4) / 384 };
    const int scol[3] = { (tid * 4) % 384, (4096 + tid * 4) % 384, (8192 + tid * 4) % 384 };

    // ---- prologue: issue chunk0 loads first ----
    float4 pre[3];
    {
        const float* xb = x + (size_t)b * NT * NC;
        #pragma unroll
        for (int k = 0; k < 3; ++k)
            pre[k] = *reinterpret_cast<const float4*>(xb + k * 4096 + tid * 4);
    }

    // ---- phase-2 job: wave j<12 owns (pass, n); gather its 12 W frags --------
    // Bw[kk] elem j = W_pass[(kk*32+8g+j)*64 + n*16+col]
    const int pass = w >> 2;         // 0=Q 1=K 2=V (w<12)
    const int n    = w & 3;
    bf16x8 Bw[12];
    if (w < 12) {
        const float* Wsel = (pass == 0) ? Wq : (pass == 1) ? Wk : Wv;
        const float* Wbase = Wsel + (size_t)(g * 8) * 64 + n * 16 + col;
        #pragma unroll
        for (int kk = 0; kk < 12; ++kk) {
            u16x8 u;
            #pragma unroll
            for (int j = 0; j < 8; ++j)
                u[j] = f2bf(Wbase[(size_t)(kk * 32 + j) * 64]);
            Bw[kk] = __builtin_bit_cast(bf16x8, u);
        }
    }

    // write chunk0 to XS0
    #pragma unroll
    for (int k = 0; k < 3; ++k) {
        u16x4 u;
        u[0] = f2bf(pre[k].x); u[1] = f2bf(pre[k].y);
        u[2] = f2bf(pre[k].z); u[3] = f2bf(pre[k].w);
        *reinterpret_cast<u16x4*>(&SM[FOFF_XS0 + srow[k] * FLDXS + scol[k]]) = u;
    }
    __syncthreads();

    // ---- main loop: 8 chunks of 32 rows, ping-pong, ONE barrier per chunk ----
    #pragma unroll 1
    for (int ch = 0; ch < 8; ++ch) {
        // issue next chunk's global loads FIRST (latency hides under compute)
        float4 nxt[3];
        if (ch < 7) {
            const float* xb = x + ((size_t)b * NT + (ch + 1) * 32) * NC;
            #pragma unroll
            for (int k = 0; k < 3; ++k)
                nxt[k] = *reinterpret_cast<const float4*>(xb + k * 4096 + tid * 4);
        }

        // compute chunk ch from buf[ch&1]
        const int xsbase = (ch & 1) ? FOFF_XS1 : FOFF_XS0;
        if (w < 12) {
            #pragma unroll
            for (int rt = 0; rt < 2; ++rt) {        // two 16-row tiles per chunk
                const int tile = ch * 2 + rt;
                f32x4 acc = (f32x4){0.f, 0.f, 0.f, 0.f};
                #pragma unroll
                for (int kk = 0; kk < 12; ++kk) {
                    const bf16x8 xf = *reinterpret_cast<const bf16x8*>(
                        &SM[xsbase + (rt * 16 + col) * FLDXS + kk * 32 + g * 8]);
                    acc = mfma16(xf, Bw[kk], acc);
                }
                const int tb = tile * 16 + g * 4;
                if (pass < 2) {
                    const int base = (pass == 0) ? FOFF_Q : FOFF_K;
                    #pragma unroll
                    for (int r = 0; r < 4; ++r)
                        SM[base + (tb + r) * FLDQK + n * 16 + col] = f2bf(acc[r]);
                } else {
                    #pragma unroll
                    for (int r = 0; r < 4; ++r)
                        SM[FOFF_VT + (n * 16 + col) * FLDVT + tb + r] = f2bf(acc[r]);
                }
            }
        }

        // write next chunk into the buffer compute(ch-1) used; its readers were
        // fenced by the previous iteration's barrier -> no hazard with compute(ch)
        if (ch < 7) {
            const int nb = ((ch + 1) & 1) ? FOFF_XS1 : FOFF_XS0;
            #pragma unroll
            for (int k = 0; k < 3; ++k) {
                u16x4 u;
                u[0] = f2bf(nxt[k].x); u[1] = f2bf(nxt[k].y);
                u[2] = f2bf(nxt[k].z); u[3] = f2bf(nxt[k].w);
                *reinterpret_cast<u16x4*>(&SM[nb + srow[k] * FLDXS + scol[k]]) = u;
            }
        }
        __syncthreads();    // publishes chunk ch+1 AND compute(ch)'s Q/K/VT tiles
    }

    // ---------------- phase 3: attention (swapped QK^T, shuffle PV) ----------
    const int hi_half = (lane >> 5) & 1;
    const int srcA = ((lane >> 4) & 1) * 32 + col;
    const int srcB = srcA + 16;

    // Q B-frags from LDS rows
    bf16x8 qb[2];
    #pragma unroll
    for (int kk = 0; kk < 2; ++kk)
        qb[kk] = *reinterpret_cast<const bf16x8*>(
            &SM[FOFF_Q + (T * 16 + col) * FLDQK + kk * 32 + g * 8]);

    // scores S^T: lane holds S[s=nt*16+4g+r][t=T*16+col]
    f32x4 sc[16];
    #pragma unroll
    for (int nt = 0; nt < 16; ++nt) {
        if (nt <= T) {
            f32x4 a = {0.f, 0.f, 0.f, 0.f};
            const bf16x8 ka0 = *reinterpret_cast<const bf16x8*>(
                &SM[FOFF_K + (nt * 16 + col) * FLDQK + g * 8]);
            const bf16x8 ka1 = *reinterpret_cast<const bf16x8*>(
                &SM[FOFF_K + (nt * 16 + col) * FLDQK + 32 + g * 8]);
            a = mfma16(ka0, qb[0], a);
            a = mfma16(ka1, qb[1], a);
            sc[nt] = a;
        }
    }

    // softmax over s for row t=col; reduce across g with 2 shuffles
    float m = -INFINITY;
    #pragma unroll
    for (int nt = 0; nt < 16; ++nt) {
        if (nt <= T) {
            #pragma unroll
            for (int r = 0; r < 4; ++r) {
                float v = sc[nt][r] * 0.125f;
                if (nt == T && (4 * g + r) > col) v = -INFINITY;   // causal
                sc[nt][r] = v;
                m = fmaxf(m, v);
            }
        }
    }
    m = fmaxf(m, __shfl_xor(m, 16));
    m = fmaxf(m, __shfl_xor(m, 32));
    float s = 0.f;
    #pragma unroll
    for (int nt = 0; nt < 16; ++nt) {
        if (nt <= T) {
            #pragma unroll
            for (int r = 0; r < 4; ++r) {
                const float p = __expf(sc[nt][r] - m);
                sc[nt][r] = p;
                s += p;
            }
        }
    }
    s += __shfl_xor(s, 16);
    s += __shfl_xor(s, 32);
    const float inv = 1.0f / s;

    // normalized P -> bf16 pairs (per nt: r0|r1, r2|r3)
    unsigned P4lo[16], P4hi[16];
    #pragma unroll
    for (int nt = 0; nt < 16; ++nt) {
        if (nt <= T) {
            P4lo[nt] = pack2(sc[nt][0] * inv, sc[nt][1] * inv);
            P4hi[nt] = pack2(sc[nt][2] * inv, sc[nt][3] * inv);
        } else { P4lo[nt] = 0u; P4hi[nt] = 0u; }
    }

    // PV: build P A-frags via shuffles (no LDS), accumulate O
    f32x4 oacc[4];
    #pragma unroll
    for (int nn = 0; nn < 4; ++nn) oacc[nn] = (f32x4){0.f, 0.f, 0.f, 0.f};
    #pragma unroll
    for (int cpv = 0; cpv < 8; ++cpv) {
        if (cpv <= (T >> 1)) {
            const unsigned a0 = __shfl(P4lo[2 * cpv],     srcA, 64);
            const unsigned a1 = __shfl(P4lo[2 * cpv + 1], srcA, 64);
            const unsigned b0 = __shfl(P4hi[2 * cpv],     srcA, 64);
            const unsigned b1 = __shfl(P4hi[2 * cpv + 1], srcA, 64);
            const unsigned c0 = __shfl(P4lo[2 * cpv],     srcB, 64);
            const unsigned c1 = __shfl(P4lo[2 * cpv + 1], srcB, 64);
            const unsigned d0 = __shfl(P4hi[2 * cpv],     srcB, 64);
            const unsigned d1 = __shfl(P4hi[2 * cpv + 1], srcB, 64);
            u32x4 wv;
            wv[0] = hi_half ? a1 : a0;
            wv[1] = hi_half ? b1 : b0;
            wv[2] = hi_half ? c1 : c0;
            wv[3] = hi_half ? d1 : d0;
            const bf16x8 pa = __builtin_bit_cast(bf16x8, wv);
            #pragma unroll
            for (int nn = 0; nn < 4; ++nn) {
                const bf16x8 vb = *reinterpret_cast<const bf16x8*>(
                    &SM[FOFF_VT + (nn * 16 + col) * FLDVT + cpv * 32 + g * 8]);
                oacc[nn] = mfma16(pa, vb, oacc[nn]);
            }
        }
    }

    // store O (P already normalized)
    #pragma unroll
    for (int nn = 0; nn < 4; ++nn)
        #pragma unroll
        for (int r = 0; r < 4; ++r)
            out[((size_t)b * NT + T * 16 + 4 * g + r) * NH + nn * 16 + col] = oacc[nn][r];
}

// ============ launcher =========================================================
extern "C" void kernel_launch(void* const* d_in, const int* in_sizes, int n_in,
                              void* d_out, int out_size, void* d_ws, size_t ws_size,
                              hipStream_t stream) {
    (void)in_sizes; (void)n_in; (void)out_size; (void)d_ws; (void)ws_size;
    const float* x  = (const float*)d_in[0];
    const float* wq = (const float*)d_in[1];
    const float* wk = (const float*)d_in[2];
    const float* wv = (const float*)d_in[3];
    float* o = (float*)d_out;

    head_v10<<<dim3(NB), dim3(1024), 0, stream>>>(x, wq, wk, wv, o);
}